// Round 8
// baseline (145.161 us; speedup 1.0000x reference)
//
#include <hip/hip_runtime.h>
#include <stdint.h>
#include <stddef.h>

#define BB 16
#define TT 2048
#define CC 64
#define NT 16      // 16 KV tiles of 128 s

typedef __attribute__((ext_vector_type(8))) short short8;
typedef __attribute__((ext_vector_type(4))) float f32x4;
typedef __attribute__((ext_vector_type(16))) float f32x16;

#if defined(__has_builtin)
#if __has_builtin(__builtin_amdgcn_exp2f)
#define EXP2(x) __builtin_amdgcn_exp2f(x)
#else
#define EXP2(x) exp2f(x)
#endif
#else
#define EXP2(x) exp2f(x)
#endif

// round-to-nearest-even f32 -> bf16 bit pattern
static __device__ __forceinline__ unsigned short f2bf(float f) {
  union { float f; unsigned int u; } v; v.f = f;
  unsigned int u = v.u;
  return (unsigned short)((u + 0x7FFFu + ((u >> 16) & 1u)) >> 16);
}

// T12 pack: 16 f32 (P column-slice in C/D layout) -> two PV A-fragment words
static __device__ __forceinline__ short8 pack_swap(
    float a0, float a1, float a2, float a3,
    float a4, float a5, float a6, float a7) {
  unsigned X, Z, Y, W;
  asm("v_cvt_pk_bf16_f32 %0, %1, %2" : "=v"(X) : "v"(a0), "v"(a1));
  asm("v_cvt_pk_bf16_f32 %0, %1, %2" : "=v"(Z) : "v"(a2), "v"(a3));
  asm("v_cvt_pk_bf16_f32 %0, %1, %2" : "=v"(Y) : "v"(a4), "v"(a5));
  asm("v_cvt_pk_bf16_f32 %0, %1, %2" : "=v"(W) : "v"(a6), "v"(a7));
  asm("v_permlane32_swap_b32 %0, %1" : "+v"(X), "+v"(Y));
  asm("v_permlane32_swap_b32 %0, %1" : "+v"(Z), "+v"(W));
  union { unsigned u[4]; short8 s; } u;
  u.u[0] = X; u.u[1] = Z; u.u[2] = Y; u.u[3] = W;
  return u.s;
}

// ---------------------------------------------------------------------------
// Prep v3: fragment-linear operand layouts + sq.
//   kfrag[b][j(64)][kc(4)][lane(64)][8] : elem = x[j*32 + (lane&31)]
//                                              [kc*16 + (lane>>5)*8 + e]
//   vfrag[b][m(128)][c(64)][sh(2)][8]   : elem = x[m*16 + sh*8 + e][c]
// Grid 1024 = 16 b x 64 j-blocks of 32 rows; 256 thr, 8 floats each.
// ---------------------------------------------------------------------------
__global__ __launch_bounds__(256, 4) void prep_kernel(
    const float* __restrict__ x, unsigned short* __restrict__ kfrag,
    unsigned short* __restrict__ vfrag, float* __restrict__ sq)
{
  __shared__ unsigned short tile[32 * 72];   // [32 t][64 c] bf16, pad 72
  const int b = blockIdx.x >> 6;
  const int j = blockIdx.x & 63;
  const int tid = threadIdx.x;
  const int r = tid >> 3, cq = tid & 7;

  const float* src = x + ((size_t)(b * TT + j * 32 + r) * CC + cq * 8);
  const f32x4 v0 = ((const f32x4*)src)[0];
  const f32x4 v1 = ((const f32x4*)src)[1];
  float ssq = v0[0]*v0[0] + v0[1]*v0[1] + v0[2]*v0[2] + v0[3]*v0[3]
            + v1[0]*v1[0] + v1[1]*v1[1] + v1[2]*v1[2] + v1[3]*v1[3];

  unsigned short h[8];
  h[0]=f2bf(v0[0]); h[1]=f2bf(v0[1]); h[2]=f2bf(v0[2]); h[3]=f2bf(v0[3]);
  h[4]=f2bf(v1[0]); h[5]=f2bf(v1[1]); h[6]=f2bf(v1[2]); h[7]=f2bf(v1[3]);
  *(short8*)(&tile[r * 72 + cq * 8]) = *(const short8*)h;

  ssq += __shfl_xor(ssq, 1); ssq += __shfl_xor(ssq, 2); ssq += __shfl_xor(ssq, 4);
  if (cq == 0) sq[(size_t)b * TT + j * 32 + r] = ssq;
  __syncthreads();

  // kfrag: coalesced short8 per thread
  {
    const int kc = tid >> 6, lane = tid & 63;
    const short8 kv = *(const short8*)(
        &tile[(lane & 31) * 72 + kc * 16 + (lane >> 5) * 8]);
    *(short8*)(kfrag + (((size_t)(b * 64 + j) * 4 + kc) * 64 + lane) * 8) = kv;
  }
  // vfrag: transpose read from LDS, coalesced short8 write
  {
    const int mh = tid >> 7, c = (tid >> 1) & 63, sh = tid & 1;
    unsigned short vh[8];
#pragma unroll
    for (int e = 0; e < 8; ++e) vh[e] = tile[(mh * 16 + sh * 8 + e) * 72 + c];
    *(short8*)(vfrag + (((size_t)(b * 128 + j * 2 + mh) * 64 + c) * 2 + sh) * 8) =
        *(const short8*)vh;
  }
}

// ---------------------------------------------------------------------------
// attn v6: barrier-free main loop with fragment-linear coalesced global loads.
// 512 thr = 8 waves (wq 2 x ws 4), 64 q-rows/block, each wave sweeps its
// 32-s window of 16 tiles. Swapped QK^T (2 chains) + T12 in-register P.
// LDS used only for the final ws-reduction.
// ---------------------------------------------------------------------------
__global__ __launch_bounds__(512, 4) void attn_kernel(
    const float* __restrict__ x, const unsigned short* __restrict__ kfrag,
    const unsigned short* __restrict__ vfrag, const float* __restrict__ sq,
    const float* __restrict__ rsig, const float* __restrict__ marg,
    float* __restrict__ out)
{
  __shared__ float RedF[8 * 2048];   // 64 KB

  const int bid = ((blockIdx.x & 7) << 6) | (blockIdx.x >> 3);  // XCD swizzle
  const int b   = bid >> 5;
  const int qb  = (bid & 31) << 6;
  const int tid = threadIdx.x;
  const int w = tid >> 6, lane = tid & 63;
  const int l31 = lane & 31, hi1 = lane >> 5;
  const int wq = w & 1, ws = w >> 1;            // ws in 0..3

  const float L2E = 1.44269504088896f;
  const float rl2 = -rsig[0] * L2E;
  const float ml2 = marg[0] * L2E;

  const unsigned short* kf_b = kfrag + (size_t)b * (64 * 4 * 64 * 8);
  const unsigned short* vf_b = vfrag + (size_t)b * (128 * 64 * 2 * 8);
  const float* sq_b = sq + (size_t)b * TT;

  const int q0w = qb + wq * 32;

  // Q B-fragments from kfrag (coalesced): col q = q0w + l31
  short8 qf[4];
  {
    const size_t jq = (size_t)(qb >> 5) + wq;
#pragma unroll
    for (int kc = 0; kc < 4; ++kc)
      qf[kc] = *(const short8*)(kf_b + ((jq * 4 + kc) * 64 + lane) * 8);
  }
  const float aq = sq_b[q0w + l31];

  f32x16 oacc[2];
#pragma unroll
  for (int ct = 0; ct < 2; ++ct)
#pragma unroll
    for (int i = 0; i < 16; ++i) oacc[ct][i] = 0.f;

  const int dQ = q0w - ws * 32;              // diagonal ownership
  const int dtile = dQ >> 7;
  const bool dvalid = ((dQ & 127) == 0) && dtile >= 0 && dtile < NT;

#pragma unroll 2
  for (int t = 0; t < NT; ++t) {
    // K A-frags: contiguous 1KB per wave per kc
    const unsigned short* kp = kf_b + ((size_t)(t * 4 + ws) * 4 * 64 * 8);
    short8 kf[4];
#pragma unroll
    for (int kc = 0; kc < 4; ++kc)
      kf[kc] = *(const short8*)(kp + (kc * 64 + lane) * 8);

    // V B-frags: contiguous 1KB per wave per (ct,kk)
    short8 vf[2][2];
#pragma unroll
    for (int ct = 0; ct < 2; ++ct)
#pragma unroll
      for (int kk = 0; kk < 2; ++kk) {
        const size_t m = (size_t)t * 8 + ws * 2 + kk;
        vf[ct][kk] = *(const short8*)(
            vf_b + ((m * 64 + ct * 32 + l31) * 2 + hi1) * 8);
      }

    // s sums of squares (broadcast, L1-resident)
    f32x4 sqv[4];
#pragma unroll
    for (int ch = 0; ch < 4; ++ch)
      sqv[ch] = *(const f32x4*)(sq_b + t * 128 + ws * 32 + ch * 8 + 4 * hi1);

    // QK^T swapped: D[s][q]; two independent chains
    f32x16 sacA, sacB;
#pragma unroll
    for (int i = 0; i < 16; ++i) { sacA[i] = 0.f; sacB[i] = 0.f; }
    sacA = __builtin_amdgcn_mfma_f32_32x32x16_bf16(kf[0], qf[0], sacA, 0, 0, 0);
    sacB = __builtin_amdgcn_mfma_f32_32x32x16_bf16(kf[1], qf[1], sacB, 0, 0, 0);
    sacA = __builtin_amdgcn_mfma_f32_32x32x16_bf16(kf[2], qf[2], sacA, 0, 0, 0);
    sacB = __builtin_amdgcn_mfma_f32_32x32x16_bf16(kf[3], qf[3], sacB, 0, 0, 0);

    // Gaussian kernel
    float p[16];
#pragma unroll
    for (int r = 0; r < 16; ++r) {
      const float s2 = sacA[r] + sacB[r];
      float d = fmaf(s2, -2.f, aq + sqv[r >> 2][r & 3]);
      d = fmaxf(d, 0.f);
      p[r] = EXP2(fmaf(d, rl2, ml2));
    }
    if (dvalid && t == dtile) {              // diagonal quadrant
#pragma unroll
      for (int r = 0; r < 16; ++r) {
        const int sl = (r & 3) + 8 * (r >> 2) + 4 * hi1;
        if (sl == l31) p[r] = 0.f;
      }
    }

    // PV A-frags in-register (T12)
    const short8 af0 = pack_swap(p[0], p[1], p[2],  p[3],  p[4],  p[5],  p[6],  p[7]);
    const short8 af1 = pack_swap(p[8], p[9], p[10], p[11], p[12], p[13], p[14], p[15]);

#pragma unroll
    for (int ct = 0; ct < 2; ++ct) {
      oacc[ct] = __builtin_amdgcn_mfma_f32_32x32x16_bf16(af0, vf[ct][0], oacc[ct], 0, 0, 0);
      oacc[ct] = __builtin_amdgcn_mfma_f32_32x32x16_bf16(af1, vf[ct][1], oacc[ct], 0, 0, 0);
    }
  }

  // -------- epilogue: all 8 waves dump partials, then vectorized reduce ----
  {
    const int base = w * 2048;
#pragma unroll
    for (int ct = 0; ct < 2; ++ct)
#pragma unroll
      for (int r = 0; r < 16; ++r) {
        const int ql = (r & 3) + 8 * (r >> 2) + 4 * hi1;
        RedF[base + ql * 64 + ct * 32 + l31] = oacc[ct][r];
      }
  }
  __syncthreads();

  // pass p covers q-rows [p*32, p*32+32) (these belonged to wq = p)
#pragma unroll
  for (int pass = 0; pass < 2; ++pass) {
    const int q  = pass * 32 + (tid >> 4);
    const int c4 = (tid & 15) * 4;
    const int off = (q & 31) * 64 + c4;
    f32x4 acc = *(const f32x4*)(&RedF[(0 * 2 + pass) * 2048 + off]);
    acc += *(const f32x4*)(&RedF[(1 * 2 + pass) * 2048 + off]);
    acc += *(const f32x4*)(&RedF[(2 * 2 + pass) * 2048 + off]);
    acc += *(const f32x4*)(&RedF[(3 * 2 + pass) * 2048 + off]);
    const size_t idx = (size_t)(b * TT + qb + q) * CC + c4;
    const f32x4 xv = *(const f32x4*)(x + idx);
    *(f32x4*)(out + idx) = acc + xv;
  }
}

// ---------------------------------------------------------------------------
extern "C" void kernel_launch(void* const* d_in, const int* in_sizes, int n_in,
                              void* d_out, int out_size, void* d_ws, size_t ws_size,
                              hipStream_t stream) {
  const float* x    = (const float*)d_in[0];
  const float* rsig = (const float*)d_in[1];
  const float* marg = (const float*)d_in[2];
  float* out = (float*)d_out;

  unsigned short* kfrag = (unsigned short*)d_ws;                   // 4 MB
  unsigned short* vfrag = kfrag + (size_t)BB * TT * CC;            // 4 MB
  float* sq = (float*)(vfrag + (size_t)BB * TT * CC);              // 128 KB

  prep_kernel<<<1024, 256, 0, stream>>>(x, kfrag, vfrag, sq);
  attn_kernel<<<512, 512, 0, stream>>>(x, kfrag, vfrag, sq, rsig, marg, out);
}

// Round 9
// 125.763 us; speedup vs baseline: 1.1542x; 1.1542x over previous
//
#include <hip/hip_runtime.h>
#include <stdint.h>
#include <stddef.h>

#define BB 16
#define TT 2048
#define CC 64
#define NT 16      // 16 KV tiles of 128 s

typedef __attribute__((ext_vector_type(8))) short short8;
typedef __attribute__((ext_vector_type(4))) short s16x4;
typedef __attribute__((ext_vector_type(4))) float f32x4;
typedef __attribute__((ext_vector_type(16))) float f32x16;

#if defined(__has_builtin)
#if __has_builtin(__builtin_amdgcn_exp2f)
#define EXP2(x) __builtin_amdgcn_exp2f(x)
#else
#define EXP2(x) exp2f(x)
#endif
#else
#define EXP2(x) exp2f(x)
#endif

// round-to-nearest-even f32 -> bf16 bit pattern
static __device__ __forceinline__ unsigned short f2bf(float f) {
  union { float f; unsigned int u; } v; v.f = f;
  unsigned int u = v.u;
  return (unsigned short)((u + 0x7FFFu + ((u >> 16) & 1u)) >> 16);
}

// T12 pack: 8 f32 -> PV A-fragment half via cvt_pk + permlane32_swap
static __device__ __forceinline__ short8 pack_swap(
    float a0, float a1, float a2, float a3,
    float a4, float a5, float a6, float a7) {
  unsigned X, Z, Y, W;
  asm("v_cvt_pk_bf16_f32 %0, %1, %2" : "=v"(X) : "v"(a0), "v"(a1));
  asm("v_cvt_pk_bf16_f32 %0, %1, %2" : "=v"(Z) : "v"(a2), "v"(a3));
  asm("v_cvt_pk_bf16_f32 %0, %1, %2" : "=v"(Y) : "v"(a4), "v"(a5));
  asm("v_cvt_pk_bf16_f32 %0, %1, %2" : "=v"(W) : "v"(a6), "v"(a7));
  asm("v_permlane32_swap_b32 %0, %1" : "+v"(X), "+v"(Y));
  asm("v_permlane32_swap_b32 %0, %1" : "+v"(Z), "+v"(W));
  union { unsigned u[4]; short8 s; } u;
  u.u[0] = X; u.u[1] = Z; u.u[2] = Y; u.u[3] = W;
  return u.s;
}

// ---------------------------------------------------------------------------
// Prep: xb = bf16(x) [B,T,C]; xbT = transposed [B,C,T]; sq = row sum of sq.
// ---------------------------------------------------------------------------
__global__ __launch_bounds__(256, 4) void prep_kernel(
    const float* __restrict__ x, unsigned short* __restrict__ xb,
    unsigned short* __restrict__ xbT, float* __restrict__ sq)
{
  __shared__ unsigned short tile[16 * 68];
  const int b   = blockIdx.x >> 7;
  const int t0  = (blockIdx.x & 127) << 4;
  const int tid = threadIdx.x;
  const int r   = tid >> 4;
  const int cg  = tid & 15;
  const int c4  = cg * 4;

  const size_t idx = (size_t)(b * TT + t0 + r) * CC + c4;
  const f32x4 v = *(const f32x4*)(x + idx);
  float ssq = v[0]*v[0] + v[1]*v[1] + v[2]*v[2] + v[3]*v[3];

  s16x4 hv;
  hv[0] = (short)f2bf(v[0]); hv[1] = (short)f2bf(v[1]);
  hv[2] = (short)f2bf(v[2]); hv[3] = (short)f2bf(v[3]);
  *(s16x4*)(xb + idx) = hv;
  *(s16x4*)(&tile[r * 68 + c4]) = hv;

  ssq += __shfl_xor(ssq, 1); ssq += __shfl_xor(ssq, 2);
  ssq += __shfl_xor(ssq, 4); ssq += __shfl_xor(ssq, 8);
  if (cg == 0) sq[(size_t)b * TT + t0 + r] = ssq;
  __syncthreads();

  const int c = tid >> 2, tq = tid & 3;
  s16x4 o;
#pragma unroll
  for (int k = 0; k < 4; ++k) o[k] = (short)tile[(tq * 4 + k) * 68 + c];
  *(s16x4*)(xbT + (size_t)(b * CC + c) * TT + t0 + tq * 4) = o;
}

// ---------------------------------------------------------------------------
// attn v7: v4 ordering (LOADT-top / compute / WRITET / barrier) with:
// 64 KB LDS exactly (2 blocks/CU), full-16 V swizzle, strength-reduced
// addressing, sq early-issued from global, lean exp math (no clamp),
// setprio around MFMA clusters, vectorized all-wave epilogue.
// 512 thr = 8 waves (wq 2 x ws 4), 64 q-rows/block, 128-s KV tiles.
// ---------------------------------------------------------------------------
__global__ __launch_bounds__(512, 4) void attn_kernel(
    const float* __restrict__ x, const unsigned short* __restrict__ xb,
    const unsigned short* __restrict__ xbT, const float* __restrict__ sq,
    const float* __restrict__ rsig, const float* __restrict__ marg,
    float* __restrict__ out)
{
  // [buf 2][ K: 128 s x 64 c (8192) | V^T: 64 c x 128 s (8192) ] = 64 KB
  __shared__ unsigned short SMEM[2][16384];

  const int bid = ((blockIdx.x & 7) << 6) | (blockIdx.x >> 3);  // XCD swizzle
  const int b   = bid >> 5;
  const int qb  = (bid & 31) << 6;
  const int tid = threadIdx.x;
  const int w = tid >> 6, lane = tid & 63;
  const int l31 = lane & 31, hi1 = lane >> 5;
  const int wq = w & 1, ws = w >> 1;            // ws in 0..3

  const float L2E = 1.44269504088896f;
  const float rl2   = -rsig[0] * L2E;
  const float ml2   = marg[0] * L2E;
  const float m2rl2 = -2.f * rl2;

  const unsigned short* xb_b  = xb  + (size_t)b * TT * CC;
  const unsigned short* xbT_b = xbT + (size_t)b * CC * TT;
  const float* sq_b = sq + (size_t)b * TT;

  const int q0w = qb + wq * 32;

  // Q B-fragments: col q = q0w + l31, k = kc*16 + hi1*8 + j
  short8 qf[4];
#pragma unroll
  for (int kc = 0; kc < 4; ++kc)
    qf[kc] = *(const short8*)(xb_b + (size_t)(q0w + l31) * CC + kc * 16 + hi1 * 8);
  const float aqml = fmaf(sq_b[q0w + l31], rl2, ml2);   // rl2*aq + ml2

  f32x16 oacc[2];
#pragma unroll
  for (int ct = 0; ct < 2; ++ct)
#pragma unroll
    for (int i = 0; i < 16; ++i) oacc[ct][i] = 0.f;

  // ---- staging geometry ----
  const int srowK = tid >> 3, slotK = tid & 7;
  const int swzK  = srowK * 64 + ((slotK ^ (srowK & 7)) * 8);
  const int srowV = tid >> 4, slotV = tid & 15;
  const int swzV  = 8192 + srowV * 128 + ((slotV ^ (srowV & 15)) * 8);

  const unsigned short* pK0 = xb_b + (size_t)srowK * CC + slotK * 8;
  const unsigned short* pK1 = xb_b + (size_t)(64 + srowK) * CC + slotK * 8;
  const unsigned short* pV0 = xbT_b + (size_t)srowV * TT + slotV * 8;
  const unsigned short* pV1 = xbT_b + (size_t)(srowV + 32) * TT + slotV * 8;

  // ---- precomputed LDS read offsets (buffer-base added per tile) ----
  int Koff[4], Voff[2][2];
#pragma unroll
  for (int kc = 0; kc < 4; ++kc)
    Koff[kc] = (ws * 32 + l31) * 64 + (((kc * 2 + hi1) ^ (l31 & 7)) * 8);
#pragma unroll
  for (int ct = 0; ct < 2; ++ct)
#pragma unroll
    for (int kk = 0; kk < 2; ++kk)
      Voff[ct][kk] = 8192 + (ct * 32 + l31) * 128 +
                     (((ws * 4 + kk * 2 + hi1) ^ (l31 & 15)) * 8);

  const float* sqp = sq_b + ws * 32 + 4 * hi1;

  const int dQ = q0w - ws * 32;              // diagonal ownership
  const int dtile = dQ >> 7;
  const bool dvalid = ((dQ & 127) == 0) && dtile >= 0 && dtile < NT;

  short8 sK0, sK1, sV0, sV1;

  // prologue: stage tile 0
  {
    sK0 = *(const short8*)(pK0);
    sK1 = *(const short8*)(pK1);
    sV0 = *(const short8*)(pV0);
    sV1 = *(const short8*)(pV1);
    unsigned short* d = &SMEM[0][0];
    *(short8*)(d + swzK)        = sK0;
    *(short8*)(d + swzK + 4096) = sK1;
    *(short8*)(d + swzV)        = sV0;
    *(short8*)(d + swzV + 4096) = sV1;
  }
  __syncthreads();

  for (int t = 0; t < NT; ++t) {
    const int bufoff = (t & 1) << 14;

    // issue next-tile global loads first (fly under compute)
    if (t + 1 < NT) {
      const size_t o = (size_t)(t + 1) * 128;
      sK0 = *(const short8*)(pK0 + o * CC);
      sK1 = *(const short8*)(pK1 + o * CC);
      sV0 = *(const short8*)(pV0 + o);
      sV1 = *(const short8*)(pV1 + o);
    }

    // s sums of squares (early-issued, off the critical chain)
    const float* sqt = sqp + t * 128;
    f32x4 sqv[4];
#pragma unroll
    for (int ch = 0; ch < 4; ++ch)
      sqv[ch] = *(const f32x4*)(sqt + ch * 8);

    const unsigned short* s = &SMEM[0][0] + bufoff;

    // QK^T swapped: D[s][q]; two independent MFMA chains
    const short8 kf0 = *(const short8*)(s + Koff[0]);
    const short8 kf1 = *(const short8*)(s + Koff[1]);
    const short8 kf2 = *(const short8*)(s + Koff[2]);
    const short8 kf3 = *(const short8*)(s + Koff[3]);
    f32x16 sacA, sacB;
#pragma unroll
    for (int i = 0; i < 16; ++i) { sacA[i] = 0.f; sacB[i] = 0.f; }
    __builtin_amdgcn_s_setprio(1);
    sacA = __builtin_amdgcn_mfma_f32_32x32x16_bf16(kf0, qf[0], sacA, 0, 0, 0);
    sacB = __builtin_amdgcn_mfma_f32_32x32x16_bf16(kf1, qf[1], sacB, 0, 0, 0);
    sacA = __builtin_amdgcn_mfma_f32_32x32x16_bf16(kf2, qf[2], sacA, 0, 0, 0);
    sacB = __builtin_amdgcn_mfma_f32_32x32x16_bf16(kf3, qf[3], sacB, 0, 0, 0);
    __builtin_amdgcn_s_setprio(0);

    // p = exp2( m2rl2*S + (rl2*as + aqml) )   [clamp dropped: |err|<0.005]
    float p[16];
#pragma unroll
    for (int r = 0; r < 16; ++r) {
      const float base = fmaf(sqv[r >> 2][r & 3], rl2, aqml);
      p[r] = EXP2(fmaf(sacA[r] + sacB[r], m2rl2, base));
    }
    if (dvalid && t == dtile) {              // diagonal quadrant
#pragma unroll
      for (int r = 0; r < 16; ++r) {
        const int sl = (r & 3) + 8 * (r >> 2) + 4 * hi1;
        if (sl == l31) p[r] = 0.f;
      }
    }

    // PV A-frags in-register (T12)
    const short8 af0 = pack_swap(p[0], p[1], p[2],  p[3],  p[4],  p[5],  p[6],  p[7]);
    const short8 af1 = pack_swap(p[8], p[9], p[10], p[11], p[12], p[13], p[14], p[15]);

    const short8 vf00 = *(const short8*)(s + Voff[0][0]);
    const short8 vf01 = *(const short8*)(s + Voff[0][1]);
    const short8 vf10 = *(const short8*)(s + Voff[1][0]);
    const short8 vf11 = *(const short8*)(s + Voff[1][1]);
    __builtin_amdgcn_s_setprio(1);
    oacc[0] = __builtin_amdgcn_mfma_f32_32x32x16_bf16(af0, vf00, oacc[0], 0, 0, 0);
    oacc[1] = __builtin_amdgcn_mfma_f32_32x32x16_bf16(af0, vf10, oacc[1], 0, 0, 0);
    oacc[0] = __builtin_amdgcn_mfma_f32_32x32x16_bf16(af1, vf01, oacc[0], 0, 0, 0);
    oacc[1] = __builtin_amdgcn_mfma_f32_32x32x16_bf16(af1, vf11, oacc[1], 0, 0, 0);
    __builtin_amdgcn_s_setprio(0);

    // write next tile into the other buffer (vmcnt drains here, post-PV)
    if (t + 1 < NT) {
      unsigned short* d = &SMEM[0][0] + (bufoff ^ 16384);
      *(short8*)(d + swzK)        = sK0;
      *(short8*)(d + swzK + 4096) = sK1;
      *(short8*)(d + swzV)        = sV0;
      *(short8*)(d + swzV + 4096) = sV1;
    }
    __syncthreads();
  }

  // -------- epilogue: all 8 waves dump partials, then vectorized reduce ----
  float* RedF = (float*)&SMEM[0][0];         // 8 x 2048 floats = 64 KB
  {
    const int base = w * 2048;
#pragma unroll
    for (int ct = 0; ct < 2; ++ct)
#pragma unroll
      for (int r = 0; r < 16; ++r) {
        const int ql = (r & 3) + 8 * (r >> 2) + 4 * hi1;
        RedF[base + ql * 64 + ct * 32 + l31] = oacc[ct][r];
      }
  }
  __syncthreads();

  // pass p covers q-rows [p*32, p*32+32) (owned by wq = p)
#pragma unroll
  for (int pass = 0; pass < 2; ++pass) {
    const int q  = pass * 32 + (tid >> 4);
    const int c4 = (tid & 15) * 4;
    const int off = (q & 31) * 64 + c4;
    f32x4 acc = *(const f32x4*)(&RedF[(0 * 2 + pass) * 2048 + off]);
    acc += *(const f32x4*)(&RedF[(1 * 2 + pass) * 2048 + off]);
    acc += *(const f32x4*)(&RedF[(2 * 2 + pass) * 2048 + off]);
    acc += *(const f32x4*)(&RedF[(3 * 2 + pass) * 2048 + off]);
    const size_t idx = (size_t)(b * TT + qb + q) * CC + c4;
    const f32x4 xv = *(const f32x4*)(x + idx);
    *(f32x4*)(out + idx) = acc + xv;
  }
}

// ---------------------------------------------------------------------------
extern "C" void kernel_launch(void* const* d_in, const int* in_sizes, int n_in,
                              void* d_out, int out_size, void* d_ws, size_t ws_size,
                              hipStream_t stream) {
  const float* x    = (const float*)d_in[0];
  const float* rsig = (const float*)d_in[1];
  const float* marg = (const float*)d_in[2];
  float* out = (float*)d_out;

  unsigned short* xb  = (unsigned short*)d_ws;                 // 4 MB
  unsigned short* xbT = xb + (size_t)BB * TT * CC;             // 4 MB
  float* sq = (float*)(xbT + (size_t)BB * TT * CC);            // 128 KB

  prep_kernel<<<2048, 256, 0, stream>>>(x, xb, xbT, sq);
  attn_kernel<<<512, 512, 0, stream>>>(x, xb, xbT, sq, rsig, marg, out);
}